// Round 1
// baseline (1138.637 us; speedup 1.0000x reference)
//
#include <hip/hip_runtime.h>
#include <math.h>

#define Nn 512
#define Ld 64
#define NB 8
#define C1 32
#define C2 25      // 3*NB+1
#define TS 16      // output tile
#define RS 18      // conv1-output region (tile + halo 1)
#define IS 20      // input region (tile + halo 2)
#define H1STRIDE 325  // 18*18=324 padded to odd stride -> conflict-free c-major access

__device__ __forceinline__ float gelu_tanh(float a) {
    float a3 = a * a * a;
    float t = tanhf(0.7978845608028654f * (a + 0.044715f * a3));
    return 0.5f * a * (1.0f + t);
}

__device__ __forceinline__ float softplus_f(float v) {
    return (v > 0.0f) ? v + log1pf(expf(-v)) : log1pf(expf(v));
}

__device__ __forceinline__ float pos_mod_2pi(float v) {
    const float T = 6.2831853071795864769f;
    float r = fmodf(v, T);
    if (r < 0.0f) r += T;
    return r;
}

__global__ __launch_bounds__(256) void csplaq_fused_kernel(
    const float* __restrict__ x,
    const float* __restrict__ c1w, const float* __restrict__ c1b,
    const float* __restrict__ c2w, const float* __restrict__ c2b,
    float* __restrict__ out_fx, float* __restrict__ out_logJ)
{
    __shared__ float s_cos[IS * IS];
    __shared__ float s_sin[IS * IS];
    __shared__ float s_h1[C1 * H1STRIDE];
    __shared__ float s_red[4];

    const float TWO_PI_F = 6.2831853071795864769f;

    int tid = threadIdx.x;
    int n = blockIdx.y;
    int tile = blockIdx.x;
    int ti = (tile >> 2) * TS;
    int tj = (tile & 3) * TS;
    const float* xn = x + n * Ld * Ld;

    // ---- stage wrapped input region; frozen-masked cos/sin ----
    for (int idx = tid; idx < IS * IS; idx += 256) {
        int li = idx / IS, lj = idx % IS;
        int gi = (ti + li - 2) & (Ld - 1);
        int gj = (tj + lj - 2) & (Ld - 1);
        float xv = xn[gi * Ld + gj];
        int pat = (gi + 2 * gj) % 3;
        float fz = (pat == 2) ? 1.0f : 0.0f;
        float sv, cv;
        sincosf(xv, &sv, &cv);
        s_cos[idx] = fz * cv;
        s_sin[idx] = fz * sv;
    }
    __syncthreads();

    // ---- conv1 (2 -> 32, 3x3) + gelu over 18x18 region ----
    // site-major: each thread owns a site, loops channels; weights are
    // wave-uniform -> scalar loads (SGPR operand of v_fma).
    for (int s0 = tid; s0 < RS * RS; s0 += 256) {
        int i = s0 / RS, j = s0 % RS;
        float v[18];
        #pragma unroll
        for (int di = 0; di < 3; ++di)
            #pragma unroll
            for (int dj = 0; dj < 3; ++dj) {
                v[di * 3 + dj]     = s_cos[(i + di) * IS + (j + dj)];
                v[9 + di * 3 + dj] = s_sin[(i + di) * IS + (j + dj)];
            }
        #pragma unroll 4
        for (int c = 0; c < C1; ++c) {
            float acc = c1b[c];
            #pragma unroll
            for (int t = 0; t < 9; ++t) {
                acc = fmaf(v[t],     c1w[c * 18 + t],     acc);
                acc = fmaf(v[9 + t], c1w[c * 18 + 9 + t], acc);
            }
            s_h1[c * H1STRIDE + s0] = gelu_tanh(acc);
        }
    }
    __syncthreads();

    // ---- conv2 (32 -> 25, 3x3): one thread per tile site ----
    int j = tid & (TS - 1);
    int i = tid >> 4;

    float acc[C2];
    #pragma unroll
    for (int co = 0; co < C2; ++co) acc[co] = c2b[co];

    #pragma unroll 1   // keep body ~2KB; full unroll (7200 FMA) would thrash I-cache
    for (int ci = 0; ci < C1; ++ci) {
        float v[9];
        const float* hp = &s_h1[ci * H1STRIDE];
        #pragma unroll
        for (int di = 0; di < 3; ++di)
            #pragma unroll
            for (int dj = 0; dj < 3; ++dj)
                v[di * 3 + dj] = hp[(i + di) * RS + (j + dj)];
        const float* wp = c2w + ci * 9;
        #pragma unroll
        for (int co = 0; co < C2; ++co) {
            const float* w = wp + co * (C1 * 9);
            float a = acc[co];
            #pragma unroll
            for (int t = 0; t < 9; ++t) a = fmaf(v[t], w[t], a);
            acc[co] = a;
        }
    }

    // ---- spline (active sites only: pat == 0) ----
    int gi = ti + i, gj = tj + j;
    float xv = xn[gi * Ld + gj];
    int pat = (gi + 2 * gj) % 3;
    float fx;
    float lj_val = 0.0f;

    if (pat == 0) {
        float kx[NB + 1], ky[NB + 1], sarr[NB + 1];
        // softmax(acc[0:8]) -> cumulative knots kx
        {
            float m = acc[0];
            #pragma unroll
            for (int q = 1; q < NB; ++q) m = fmaxf(m, acc[q]);
            float e[NB], ssum = 0.0f;
            #pragma unroll
            for (int q = 0; q < NB; ++q) { e[q] = expf(acc[q] - m); ssum += e[q]; }
            float inv = TWO_PI_F / ssum;
            float run = 0.0f;
            kx[0] = 0.0f;
            #pragma unroll
            for (int q = 0; q < NB; ++q) { run += e[q]; kx[q + 1] = run * inv; }
        }
        // softmax(acc[8:16]) -> ky
        {
            float m = acc[NB];
            #pragma unroll
            for (int q = 1; q < NB; ++q) m = fmaxf(m, acc[NB + q]);
            float e[NB], ssum = 0.0f;
            #pragma unroll
            for (int q = 0; q < NB; ++q) { e[q] = expf(acc[NB + q] - m); ssum += e[q]; }
            float inv = TWO_PI_F / ssum;
            float run = 0.0f;
            ky[0] = 0.0f;
            #pragma unroll
            for (int q = 0; q < NB; ++q) { run += e[q]; ky[q + 1] = run * inv; }
        }
        // softplus derivatives, periodic: s[8] = s[0]
        #pragma unroll
        for (int q = 0; q < NB; ++q) sarr[q] = softplus_f(acc[2 * NB + q]);
        sarr[NB] = sarr[0];
        float t_out = acc[3 * NB];

        float x1 = pos_mod_2pi(xv);
        int k = 0;
        #pragma unroll
        for (int q = 1; q <= NB - 1; ++q) k += (x1 >= kx[q]) ? 1 : 0;

        // register-array gather via select chain (avoid scratch)
        float kxk = 0.f, kxk1 = 0.f, kyk = 0.f, kyk1 = 0.f, sk = 0.f, sk1 = 0.f;
        #pragma unroll
        for (int q = 0; q <= NB; ++q) {
            if (q == k)     { kxk = kx[q];  kyk = ky[q];  sk = sarr[q]; }
            if (q == k + 1) { kxk1 = kx[q]; kyk1 = ky[q]; sk1 = sarr[q]; }
        }

        float wk = kxk1 - kxk;
        float hk = kyk1 - kyk;
        float slope = hk / wk;
        float xi = (x1 - kxk) / wk;
        xi = fminf(fmaxf(xi, 0.0f), 1.0f);
        float om = 1.0f - xi;
        float den = slope + (sk1 + sk - 2.0f * slope) * xi * om;
        float y = kyk + hk * (slope * xi * xi + sk * xi * om) / den;
        float num = slope * slope * (sk1 * xi * xi + 2.0f * slope * xi * om + sk * om * om);
        lj_val = logf(num) - 2.0f * logf(den);

        fx = pos_mod_2pi(y + t_out);
    } else {
        fx = xv;   // passive + frozen sites pass through
    }

    out_fx[n * Ld * Ld + gi * Ld + gj] = fx;

    // ---- logJ reduction: wave shuffle -> LDS -> one atomic per block ----
    float r = lj_val;
    #pragma unroll
    for (int off = 32; off > 0; off >>= 1) r += __shfl_down(r, off, 64);
    int lane = tid & 63, wv = tid >> 6;
    if (lane == 0) s_red[wv] = r;
    __syncthreads();
    if (tid == 0) {
        atomicAdd(&out_logJ[n], s_red[0] + s_red[1] + s_red[2] + s_red[3]);
    }
}

extern "C" void kernel_launch(void* const* d_in, const int* in_sizes, int n_in,
                              void* d_out, int out_size, void* d_ws, size_t ws_size,
                              hipStream_t stream) {
    const float* x   = (const float*)d_in[0];
    // d_in[1..3] are the masks; recomputed analytically ((i+2j)%3) -> exact
    const float* c1w = (const float*)d_in[4];
    const float* c1b = (const float*)d_in[5];
    const float* c2w = (const float*)d_in[6];
    const float* c2b = (const float*)d_in[7];

    float* out_fx   = (float*)d_out;
    float* out_logJ = out_fx + (size_t)Nn * Ld * Ld;

    // logJ tail is accumulated with atomics; harness poisons d_out each call
    hipMemsetAsync(out_logJ, 0, Nn * sizeof(float), stream);

    dim3 grid(16, Nn);
    csplaq_fused_kernel<<<grid, 256, 0, stream>>>(x, c1w, c1b, c2w, c2b, out_fx, out_logJ);
}

// Round 4
// 440.202 us; speedup vs baseline: 2.5866x; 2.5866x over previous
//
#include <hip/hip_runtime.h>
#include <math.h>

#define Nn 512
#define Ld 64
#define NB 8
#define C1 32
#define C2 25      // 3*NB+1
#define CHUNK 8    // conv1 output channels staged in LDS at a time

#define ICOLS 68   // input cols incl. halo 2 each side (wrapped)
#define ISTR  69   // +1 pad
#define IROWSMAX 16
#define HCOLS 66   // h1 cols incl. halo 1 each side
#define HSTR  67   // +1 pad  (USED BY BOTH writer and reader -- r3 bug was 66 vs 67)
#define HPLANE 945 // >= 14*67 = 938

// ---- round-1 verbatim math (bit-identical to the passing kernel) ----
__device__ __forceinline__ float gelu_tanh(float a) {
    float a3 = a * a * a;
    float t = tanhf(0.7978845608028654f * (a + 0.044715f * a3));
    return 0.5f * a * (1.0f + t);
}

__device__ __forceinline__ float softplus_f(float v) {
    return (v > 0.0f) ? v + log1pf(expf(-v)) : log1pf(expf(v));
}

__device__ __forceinline__ float pos_mod_2pi(float v) {
    const float T = 6.2831853071795864769f;
    float r = fmodf(v, T);
    if (r < 0.0f) r += T;
    return r;
}

__global__ __launch_bounds__(256, 4) void csplaq_v4_kernel(
    const float* __restrict__ x,
    const float* __restrict__ c1w, const float* __restrict__ c1b,
    const float* __restrict__ c2w, const float* __restrict__ c2b,
    float* __restrict__ out_fx, float* __restrict__ out_logJ)
{
    __shared__ float s_cos[IROWSMAX * ISTR];
    __shared__ float s_sin[IROWSMAX * ISTR];
    __shared__ float s_h1[CHUNK * HPLANE];
    __shared__ float s_red[4];

    const float TWO_PI_F = 6.2831853071795864769f;

    const int tid  = threadIdx.x;
    const int band = blockIdx.x;            // 0..5
    const int n    = blockIdx.y;
    const int r0   = band * 12;             // multiple of 3
    const int R    = (band == 5) ? 4 : 12;  // rows in this band
    const int rows_in  = R + 4;
    const int nsite_h  = (R + 2) * HCOLS;
    const int n_active = (R == 12) ? 256 : 86;
    const float* xn = x + n * Ld * Ld;

    // ---- stage frozen-masked cos/sin, full-width wrapped band ----
    for (int idx = tid; idx < rows_in * ICOLS; idx += 256) {
        int li = idx / ICOLS, uu = idx - li * ICOLS;
        int gi = (r0 - 2 + li) & 63;
        int gj = (uu - 2) & 63;
        float xv = xn[gi * Ld + gj];
        int pat = (gi + 2 * gj) % 3;
        float sv, cv;
        sincosf(xv, &sv, &cv);
        float fz = (pat == 2) ? 1.0f : 0.0f;
        s_cos[li * ISTR + uu] = fz * cv;
        s_sin[li * ISTR + uu] = fz * sv;
    }

    // ---- thread -> active site (rows 3g,3g+1,3g+2 hold 22,21,21 actives) ----
    int g3 = tid >> 6, u = tid & 63;
    int rsel  = (u >= 22) + (u >= 43);
    int ubase = (rsel == 2) ? 43 : ((rsel == 1) ? 22 : 0);
    int rr = 3 * g3 + rsel;                 // local band row of active site
    int cc = 3 * (u - ubase) + rsel;        // global col (col ≡ row mod 3)
    bool is_act = (tid < n_active);

    float acc[C2];
    #pragma unroll
    for (int co = 0; co < C2; ++co) acc[co] = c2b[co];

    // ---- ci-chunked conv1 -> LDS -> conv2 partial accumulation ----
    for (int c0 = 0; c0 < C1; c0 += CHUNK) {
        __syncthreads();   // staging ready / prev chunk's readers done
        for (int s = tid; s < nsite_h; s += 256) {
            int h = s / HCOLS, j = s - h * HCOLS;
            float v[18];
            #pragma unroll
            for (int di = 0; di < 3; ++di)
                #pragma unroll
                for (int dj = 0; dj < 3; ++dj) {
                    int a = (h + di) * ISTR + (j + dj);
                    v[di * 3 + dj]     = s_cos[a];
                    v[9 + di * 3 + dj] = s_sin[a];
                }
            #pragma unroll
            for (int c = 0; c < CHUNK; ++c) {
                const float* w = c1w + (c0 + c) * 18;   // uniform -> s_load
                float a1 = c1b[c0 + c];
                #pragma unroll
                for (int t = 0; t < 9; ++t) {
                    a1 = fmaf(v[t],     w[t],     a1);
                    a1 = fmaf(v[9 + t], w[9 + t], a1);
                }
                // FIX: store with HSTR stride to match the reader
                s_h1[c * HPLANE + h * HSTR + j] = gelu_tanh(a1);
            }
        }
        __syncthreads();
        if (is_act) {
            #pragma unroll 1
            for (int c = 0; c < CHUNK; ++c) {
                int ci = c0 + c;
                float v[9];
                const float* hp = s_h1 + c * HPLANE + rr * HSTR + cc;
                #pragma unroll
                for (int di = 0; di < 3; ++di)
                    #pragma unroll
                    for (int dj = 0; dj < 3; ++dj)
                        v[di * 3 + dj] = hp[di * HSTR + dj];
                const float* wp = c2w + ci * 9;
                #pragma unroll
                for (int co = 0; co < C2; ++co) {
                    const float* w = wp + co * (C1 * 9);  // uniform -> s_load
                    float a2 = acc[co];
                    #pragma unroll
                    for (int t = 0; t < 9; ++t) a2 = fmaf(v[t], w[t], a2);
                    acc[co] = a2;
                }
            }
        }
    }

    // ---- passive/frozen pass-through ----
    float* outn = out_fx + n * Ld * Ld;
    for (int idx = tid; idx < R * 64; idx += 256) {
        int lr = idx >> 6, c = idx & 63;
        int gi = r0 + lr;
        int pat = (gi + 2 * c) % 3;
        float xv = xn[gi * Ld + c];
        if (pat != 0) outn[gi * Ld + c] = xv;
    }

    // ---- spline at the active site (round-1 exact math) ----
    float lj_val = 0.0f;
    if (is_act) {
        int gi = r0 + rr;
        float xv = xn[gi * Ld + cc];

        float kx[NB + 1], ky[NB + 1], sar[NB + 1];
        {
            float m = acc[0];
            #pragma unroll
            for (int q = 1; q < NB; ++q) m = fmaxf(m, acc[q]);
            float e[NB], ssum = 0.0f;
            #pragma unroll
            for (int q = 0; q < NB; ++q) { e[q] = expf(acc[q] - m); ssum += e[q]; }
            float inv = TWO_PI_F / ssum;
            float run = 0.0f;
            kx[0] = 0.0f;
            #pragma unroll
            for (int q = 0; q < NB; ++q) { run += e[q]; kx[q + 1] = run * inv; }
        }
        {
            float m = acc[NB];
            #pragma unroll
            for (int q = 1; q < NB; ++q) m = fmaxf(m, acc[NB + q]);
            float e[NB], ssum = 0.0f;
            #pragma unroll
            for (int q = 0; q < NB; ++q) { e[q] = expf(acc[NB + q] - m); ssum += e[q]; }
            float inv = TWO_PI_F / ssum;
            float run = 0.0f;
            ky[0] = 0.0f;
            #pragma unroll
            for (int q = 0; q < NB; ++q) { run += e[q]; ky[q + 1] = run * inv; }
        }
        #pragma unroll
        for (int q = 0; q < NB; ++q) sar[q] = softplus_f(acc[2 * NB + q]);
        sar[NB] = sar[0];
        float t_out = acc[3 * NB];

        float x1 = pos_mod_2pi(xv);
        int k = 0;
        #pragma unroll
        for (int q = 1; q <= NB - 1; ++q) k += (x1 >= kx[q]) ? 1 : 0;

        float kxk = 0.f, kxk1 = 0.f, kyk = 0.f, kyk1 = 0.f, sk = 0.f, sk1 = 0.f;
        #pragma unroll
        for (int q = 0; q <= NB; ++q) {
            if (q == k)     { kxk = kx[q];  kyk = ky[q];  sk  = sar[q]; }
            if (q == k + 1) { kxk1 = kx[q]; kyk1 = ky[q]; sk1 = sar[q]; }
        }

        float wk = kxk1 - kxk;
        float hk = kyk1 - kyk;
        float slope = hk / wk;
        float xi = (x1 - kxk) / wk;
        xi = fminf(fmaxf(xi, 0.0f), 1.0f);
        float om = 1.0f - xi;
        float den = slope + (sk1 + sk - 2.0f * slope) * xi * om;
        float y = kyk + hk * (slope * xi * xi + sk * xi * om) / den;
        float num = slope * slope * (sk1 * xi * xi + 2.0f * slope * xi * om + sk * om * om);
        lj_val = logf(num) - 2.0f * logf(den);

        outn[gi * Ld + cc] = pos_mod_2pi(y + t_out);
    }

    // ---- logJ: wave shuffle -> LDS -> one atomic per block ----
    float r = lj_val;
    #pragma unroll
    for (int off = 32; off > 0; off >>= 1) r += __shfl_down(r, off, 64);
    int lane = tid & 63, wv = tid >> 6;
    if (lane == 0) s_red[wv] = r;
    __syncthreads();
    if (tid == 0)
        atomicAdd(&out_logJ[n], s_red[0] + s_red[1] + s_red[2] + s_red[3]);
}

extern "C" void kernel_launch(void* const* d_in, const int* in_sizes, int n_in,
                              void* d_out, int out_size, void* d_ws, size_t ws_size,
                              hipStream_t stream) {
    const float* x   = (const float*)d_in[0];
    // d_in[1..3] masks: recomputed analytically ((i+2j)%3) -> exact
    const float* c1w = (const float*)d_in[4];
    const float* c1b = (const float*)d_in[5];
    const float* c2w = (const float*)d_in[6];
    const float* c2b = (const float*)d_in[7];

    float* out_fx   = (float*)d_out;
    float* out_logJ = out_fx + (size_t)Nn * Ld * Ld;

    hipMemsetAsync(out_logJ, 0, Nn * sizeof(float), stream);

    dim3 grid(6, Nn);   // 6 row-bands (5x12 + 1x4) x 512 samples
    csplaq_v4_kernel<<<grid, 256, 0, stream>>>(x, c1w, c1b, c2w, c2b, out_fx, out_logJ);
}

// Round 5
// 396.665 us; speedup vs baseline: 2.8705x; 1.1098x over previous
//
#include <hip/hip_runtime.h>
#include <math.h>

#define Nn 512
#define Ld 64
#define NB 8
#define C1 32
#define C2 25      // 3*NB+1

// ---- exact math (bit-identical to passing round-4 kernel) ----
__device__ __forceinline__ float gelu_tanh(float a) {
    float a3 = a * a * a;
    float t = tanhf(0.7978845608028654f * (a + 0.044715f * a3));
    return 0.5f * a * (1.0f + t);
}

__device__ __forceinline__ float softplus_f(float v) {
    return (v > 0.0f) ? v + log1pf(expf(-v)) : log1pf(expf(v));
}

__device__ __forceinline__ float pos_mod_2pi(float v) {
    const float T = 6.2831853071795864769f;
    float r = fmodf(v, T);
    if (r < 0.0f) r += T;
    return r;
}

// ================= K1: conv1 + gelu -> global h1 [n][c][64][64] =================
__global__ __launch_bounds__(256, 8) void k1_conv1_kernel(
    const float* __restrict__ x,
    const float* __restrict__ c1w, const float* __restrict__ c1b,
    float* __restrict__ h1g)
{
    __shared__ float s_cos[8 * 69];
    __shared__ float s_sin[8 * 69];

    const int tid = threadIdx.x;
    const int rb  = blockIdx.x;      // 0..15 -> 4-row band
    const int n   = blockIdx.y;
    const int r0k = rb * 4;
    const float* xn = x + n * 4096;

    // stage frozen-masked cos/sin: rows r0k-2..r0k+5, cols -2..65 (wrapped)
    for (int idx = tid; idx < 8 * 68; idx += 256) {
        int li = idx / 68, lj = idx - li * 68;
        int gi = (r0k - 2 + li) & 63;
        int gj = (lj - 2) & 63;
        float xv = xn[gi * 64 + gj];
        int pat = (gi + 2 * gj) % 3;
        float sv, cv;
        sincosf(xv, &sv, &cv);
        float fz = (pat == 2) ? 1.0f : 0.0f;
        s_cos[li * 69 + lj] = fz * cv;
        s_sin[li * 69 + lj] = fz * sv;
    }
    __syncthreads();

    const int gj = tid & 63, lrow = tid >> 6;
    const int gi = r0k + lrow;

    float v[18];
    #pragma unroll
    for (int di = 0; di < 3; ++di)
        #pragma unroll
        for (int dj = 0; dj < 3; ++dj) {
            int a = (lrow + 1 + di) * 69 + (gj + 1 + dj);
            v[di * 3 + dj]     = s_cos[a];
            v[9 + di * 3 + dj] = s_sin[a];
        }

    float* outp = h1g + (size_t)n * C1 * 4096 + gi * 64 + gj;
    #pragma unroll 4
    for (int c = 0; c < C1; ++c) {
        const float* w = c1w + c * 18;   // uniform -> s_load
        float a1 = c1b[c];
        #pragma unroll
        for (int t = 0; t < 9; ++t) {    // cos/sin interleaved per tap == r4 order
            a1 = fmaf(v[t],     w[t],     a1);
            a1 = fmaf(v[9 + t], w[9 + t], a1);
        }
        outp[(size_t)c * 4096] = gelu_tanh(a1);   // coalesced 256B per wave-row
    }
}

// ================= K2: conv2 + spline + passthrough + logJ =================
#define K2CH 4
#define K2PLANE (14 * 64)   // 896 floats per staged channel plane

__global__ __launch_bounds__(256, 8) void k2_conv2_spline_kernel(
    const float* __restrict__ x, const float* __restrict__ h1g,
    const float* __restrict__ c2w, const float* __restrict__ c2b,
    float* __restrict__ out_fx, float* __restrict__ out_logJ)
{
    __shared__ float s_h1[K2CH * K2PLANE];   // 14336 B -> 8+ blocks/CU
    __shared__ float s_red[4];

    const float TWO_PI_F = 6.2831853071795864769f;

    const int tid  = threadIdx.x;
    const int band = blockIdx.x;            // 0..5
    const int n    = blockIdx.y;
    const int r0   = band * 12;
    const int R    = (band == 5) ? 4 : 12;
    const int rows_l   = R + 2;             // staged rows (14 or 6)
    const int n_active = (R == 12) ? 256 : 86;
    const float* xn  = x + n * 4096;
    const float* h1n = h1g + (size_t)n * C1 * 4096;

    // active-site mapping: rows 3g,3g+1,3g+2 hold 22,21,21 actives, col≡row mod 3
    int g3 = tid >> 6, u = tid & 63;
    int rsel  = (u >= 22) + (u >= 43);
    int ubase = (rsel == 2) ? 43 : ((rsel == 1) ? 22 : 0);
    int rr = 3 * g3 + rsel;                 // local band row
    int cc = 3 * (u - ubase) + rsel;        // global col
    bool is_act = (tid < n_active);
    int jm = (cc + 63) & 63, jp = (cc + 1) & 63;   // wrapped window cols

    float acc[C2];
    #pragma unroll
    for (int co = 0; co < C2; ++co) acc[co] = c2b[co];

    for (int c0 = 0; c0 < C1; c0 += K2CH) {
        __syncthreads();
        // stage K2CH channel planes, rows r0-1..r0+R (wrapped), full 64 cols
        int nf4 = K2CH * rows_l * 16;
        for (int f = tid; f < nf4; f += 256) {
            int c   = f / (rows_l * 16);
            int rem = f - c * (rows_l * 16);
            int r = rem >> 4, cg = rem & 15;
            int grow = (r0 - 1 + r) & 63;
            float4 src = *(const float4*)(h1n + (size_t)(c0 + c) * 4096 + grow * 64 + cg * 4);
            *(float4*)(&s_h1[c * K2PLANE + r * 64 + cg * 4]) = src;
        }
        __syncthreads();
        if (is_act) {
            #pragma unroll 1
            for (int c = 0; c < K2CH; ++c) {
                int ci = c0 + c;
                float v[9];
                #pragma unroll
                for (int di = 0; di < 3; ++di) {
                    // site gi=r0+rr -> staged local row rr+1; window rows rr+di
                    const float* rowp = s_h1 + c * K2PLANE + (rr + di) * 64;
                    v[di * 3 + 0] = rowp[jm];
                    v[di * 3 + 1] = rowp[cc];
                    v[di * 3 + 2] = rowp[jp];
                }
                const float* wp = c2w + ci * 9;
                #pragma unroll
                for (int co = 0; co < C2; ++co) {
                    const float* w = wp + co * (C1 * 9);  // uniform -> s_load
                    float a2 = acc[co];
                    #pragma unroll
                    for (int t = 0; t < 9; ++t) a2 = fmaf(v[t], w[t], a2);
                    acc[co] = a2;
                }
            }
        }
    }

    // ---- passive/frozen pass-through ----
    float* outn = out_fx + n * 4096;
    for (int idx = tid; idx < R * 64; idx += 256) {
        int lr = idx >> 6, c = idx & 63;
        int gi = r0 + lr;
        int pat = (gi + 2 * c) % 3;
        float xv = xn[gi * 64 + c];
        if (pat != 0) outn[gi * 64 + c] = xv;
    }

    // ---- spline at the active site (exact math, r4-identical) ----
    float lj_val = 0.0f;
    if (is_act) {
        int gi = r0 + rr;
        float xv = xn[gi * 64 + cc];

        float kx[NB + 1], ky[NB + 1], sar[NB + 1];
        {
            float m = acc[0];
            #pragma unroll
            for (int q = 1; q < NB; ++q) m = fmaxf(m, acc[q]);
            float e[NB], ssum = 0.0f;
            #pragma unroll
            for (int q = 0; q < NB; ++q) { e[q] = expf(acc[q] - m); ssum += e[q]; }
            float inv = TWO_PI_F / ssum;
            float run = 0.0f;
            kx[0] = 0.0f;
            #pragma unroll
            for (int q = 0; q < NB; ++q) { run += e[q]; kx[q + 1] = run * inv; }
        }
        {
            float m = acc[NB];
            #pragma unroll
            for (int q = 1; q < NB; ++q) m = fmaxf(m, acc[NB + q]);
            float e[NB], ssum = 0.0f;
            #pragma unroll
            for (int q = 0; q < NB; ++q) { e[q] = expf(acc[NB + q] - m); ssum += e[q]; }
            float inv = TWO_PI_F / ssum;
            float run = 0.0f;
            ky[0] = 0.0f;
            #pragma unroll
            for (int q = 0; q < NB; ++q) { run += e[q]; ky[q + 1] = run * inv; }
        }
        #pragma unroll
        for (int q = 0; q < NB; ++q) sar[q] = softplus_f(acc[2 * NB + q]);
        sar[NB] = sar[0];
        float t_out = acc[3 * NB];

        float x1 = pos_mod_2pi(xv);
        int k = 0;
        #pragma unroll
        for (int q = 1; q <= NB - 1; ++q) k += (x1 >= kx[q]) ? 1 : 0;

        float kxk = 0.f, kxk1 = 0.f, kyk = 0.f, kyk1 = 0.f, sk = 0.f, sk1 = 0.f;
        #pragma unroll
        for (int q = 0; q <= NB; ++q) {
            if (q == k)     { kxk = kx[q];  kyk = ky[q];  sk  = sar[q]; }
            if (q == k + 1) { kxk1 = kx[q]; kyk1 = ky[q]; sk1 = sar[q]; }
        }

        float wk = kxk1 - kxk;
        float hk = kyk1 - kyk;
        float slope = hk / wk;
        float xi = (x1 - kxk) / wk;
        xi = fminf(fmaxf(xi, 0.0f), 1.0f);
        float om = 1.0f - xi;
        float den = slope + (sk1 + sk - 2.0f * slope) * xi * om;
        float y = kyk + hk * (slope * xi * xi + sk * xi * om) / den;
        float num = slope * slope * (sk1 * xi * xi + 2.0f * slope * xi * om + sk * om * om);
        lj_val = logf(num) - 2.0f * logf(den);

        outn[gi * 64 + cc] = pos_mod_2pi(y + t_out);
    }

    // ---- logJ: wave shuffle -> LDS -> one atomic per block ----
    float r = lj_val;
    #pragma unroll
    for (int off = 32; off > 0; off >>= 1) r += __shfl_down(r, off, 64);
    int lane = tid & 63, wv = tid >> 6;
    if (lane == 0) s_red[wv] = r;
    __syncthreads();
    if (tid == 0)
        atomicAdd(&out_logJ[n], s_red[0] + s_red[1] + s_red[2] + s_red[3]);
}

// ================= fallback: round-4 fused kernel (if ws too small) =================
#define CHUNK 8
#define ICOLS 68
#define ISTR  69
#define IROWSMAX 16
#define HCOLS 66
#define HSTR  67
#define HPLANE 945

__global__ __launch_bounds__(256, 4) void csplaq_v4_kernel(
    const float* __restrict__ x,
    const float* __restrict__ c1w, const float* __restrict__ c1b,
    const float* __restrict__ c2w, const float* __restrict__ c2b,
    float* __restrict__ out_fx, float* __restrict__ out_logJ)
{
    __shared__ float s_cos[IROWSMAX * ISTR];
    __shared__ float s_sin[IROWSMAX * ISTR];
    __shared__ float s_h1[CHUNK * HPLANE];
    __shared__ float s_red[4];

    const float TWO_PI_F = 6.2831853071795864769f;
    const int tid  = threadIdx.x;
    const int band = blockIdx.x;
    const int n    = blockIdx.y;
    const int r0   = band * 12;
    const int R    = (band == 5) ? 4 : 12;
    const int rows_in  = R + 4;
    const int nsite_h  = (R + 2) * HCOLS;
    const int n_active = (R == 12) ? 256 : 86;
    const float* xn = x + n * Ld * Ld;

    for (int idx = tid; idx < rows_in * ICOLS; idx += 256) {
        int li = idx / ICOLS, uu = idx - li * ICOLS;
        int gi = (r0 - 2 + li) & 63;
        int gj = (uu - 2) & 63;
        float xv = xn[gi * Ld + gj];
        int pat = (gi + 2 * gj) % 3;
        float sv, cv;
        sincosf(xv, &sv, &cv);
        float fz = (pat == 2) ? 1.0f : 0.0f;
        s_cos[li * ISTR + uu] = fz * cv;
        s_sin[li * ISTR + uu] = fz * sv;
    }

    int g3 = tid >> 6, u = tid & 63;
    int rsel  = (u >= 22) + (u >= 43);
    int ubase = (rsel == 2) ? 43 : ((rsel == 1) ? 22 : 0);
    int rr = 3 * g3 + rsel;
    int cc = 3 * (u - ubase) + rsel;
    bool is_act = (tid < n_active);

    float acc[C2];
    #pragma unroll
    for (int co = 0; co < C2; ++co) acc[co] = c2b[co];

    for (int c0 = 0; c0 < C1; c0 += CHUNK) {
        __syncthreads();
        for (int s = tid; s < nsite_h; s += 256) {
            int h = s / HCOLS, j = s - h * HCOLS;
            float v[18];
            #pragma unroll
            for (int di = 0; di < 3; ++di)
                #pragma unroll
                for (int dj = 0; dj < 3; ++dj) {
                    int a = (h + di) * ISTR + (j + dj);
                    v[di * 3 + dj]     = s_cos[a];
                    v[9 + di * 3 + dj] = s_sin[a];
                }
            #pragma unroll
            for (int c = 0; c < CHUNK; ++c) {
                const float* w = c1w + (c0 + c) * 18;
                float a1 = c1b[c0 + c];
                #pragma unroll
                for (int t = 0; t < 9; ++t) {
                    a1 = fmaf(v[t],     w[t],     a1);
                    a1 = fmaf(v[9 + t], w[9 + t], a1);
                }
                s_h1[c * HPLANE + h * HSTR + j] = gelu_tanh(a1);
            }
        }
        __syncthreads();
        if (is_act) {
            #pragma unroll 1
            for (int c = 0; c < CHUNK; ++c) {
                int ci = c0 + c;
                float v[9];
                const float* hp = s_h1 + c * HPLANE + rr * HSTR + cc;
                #pragma unroll
                for (int di = 0; di < 3; ++di)
                    #pragma unroll
                    for (int dj = 0; dj < 3; ++dj)
                        v[di * 3 + dj] = hp[di * HSTR + dj];
                const float* wp = c2w + ci * 9;
                #pragma unroll
                for (int co = 0; co < C2; ++co) {
                    const float* w = wp + co * (C1 * 9);
                    float a2 = acc[co];
                    #pragma unroll
                    for (int t = 0; t < 9; ++t) a2 = fmaf(v[t], w[t], a2);
                    acc[co] = a2;
                }
            }
        }
    }

    float* outn = out_fx + n * Ld * Ld;
    for (int idx = tid; idx < R * 64; idx += 256) {
        int lr = idx >> 6, c = idx & 63;
        int gi = r0 + lr;
        int pat = (gi + 2 * c) % 3;
        float xv = xn[gi * Ld + c];
        if (pat != 0) outn[gi * Ld + c] = xv;
    }

    float lj_val = 0.0f;
    if (is_act) {
        int gi = r0 + rr;
        float xv = xn[gi * Ld + cc];
        float kx[NB + 1], ky[NB + 1], sar[NB + 1];
        {
            float m = acc[0];
            #pragma unroll
            for (int q = 1; q < NB; ++q) m = fmaxf(m, acc[q]);
            float e[NB], ssum = 0.0f;
            #pragma unroll
            for (int q = 0; q < NB; ++q) { e[q] = expf(acc[q] - m); ssum += e[q]; }
            float inv = TWO_PI_F / ssum;
            float run = 0.0f;
            kx[0] = 0.0f;
            #pragma unroll
            for (int q = 0; q < NB; ++q) { run += e[q]; kx[q + 1] = run * inv; }
        }
        {
            float m = acc[NB];
            #pragma unroll
            for (int q = 1; q < NB; ++q) m = fmaxf(m, acc[NB + q]);
            float e[NB], ssum = 0.0f;
            #pragma unroll
            for (int q = 0; q < NB; ++q) { e[q] = expf(acc[NB + q] - m); ssum += e[q]; }
            float inv = TWO_PI_F / ssum;
            float run = 0.0f;
            ky[0] = 0.0f;
            #pragma unroll
            for (int q = 0; q < NB; ++q) { run += e[q]; ky[q + 1] = run * inv; }
        }
        #pragma unroll
        for (int q = 0; q < NB; ++q) sar[q] = softplus_f(acc[2 * NB + q]);
        sar[NB] = sar[0];
        float t_out = acc[3 * NB];

        float x1 = pos_mod_2pi(xv);
        int k = 0;
        #pragma unroll
        for (int q = 1; q <= NB - 1; ++q) k += (x1 >= kx[q]) ? 1 : 0;

        float kxk = 0.f, kxk1 = 0.f, kyk = 0.f, kyk1 = 0.f, sk = 0.f, sk1 = 0.f;
        #pragma unroll
        for (int q = 0; q <= NB; ++q) {
            if (q == k)     { kxk = kx[q];  kyk = ky[q];  sk  = sar[q]; }
            if (q == k + 1) { kxk1 = kx[q]; kyk1 = ky[q]; sk1 = sar[q]; }
        }

        float wk = kxk1 - kxk;
        float hk = kyk1 - kyk;
        float slope = hk / wk;
        float xi = (x1 - kxk) / wk;
        xi = fminf(fmaxf(xi, 0.0f), 1.0f);
        float om = 1.0f - xi;
        float den = slope + (sk1 + sk - 2.0f * slope) * xi * om;
        float y = kyk + hk * (slope * xi * xi + sk * xi * om) / den;
        float num = slope * slope * (sk1 * xi * xi + 2.0f * slope * xi * om + sk * om * om);
        lj_val = logf(num) - 2.0f * logf(den);

        outn[gi * Ld + cc] = pos_mod_2pi(y + t_out);
    }

    float r = lj_val;
    #pragma unroll
    for (int off = 32; off > 0; off >>= 1) r += __shfl_down(r, off, 64);
    int lane = tid & 63, wv = tid >> 6;
    if (lane == 0) s_red[wv] = r;
    __syncthreads();
    if (tid == 0)
        atomicAdd(&out_logJ[n], s_red[0] + s_red[1] + s_red[2] + s_red[3]);
}

extern "C" void kernel_launch(void* const* d_in, const int* in_sizes, int n_in,
                              void* d_out, int out_size, void* d_ws, size_t ws_size,
                              hipStream_t stream) {
    const float* x   = (const float*)d_in[0];
    // d_in[1..3] masks: recomputed analytically ((i+2j)%3) -> exact
    const float* c1w = (const float*)d_in[4];
    const float* c1b = (const float*)d_in[5];
    const float* c2w = (const float*)d_in[6];
    const float* c2b = (const float*)d_in[7];

    float* out_fx   = (float*)d_out;
    float* out_logJ = out_fx + (size_t)Nn * Ld * Ld;

    hipMemsetAsync(out_logJ, 0, Nn * sizeof(float), stream);

    const size_t h1_bytes = (size_t)Nn * C1 * Ld * Ld * sizeof(float);  // 256 MiB
    if (ws_size >= h1_bytes) {
        float* h1g = (float*)d_ws;
        dim3 g1(16, Nn);
        k1_conv1_kernel<<<g1, 256, 0, stream>>>(x, c1w, c1b, h1g);
        dim3 g2(6, Nn);
        k2_conv2_spline_kernel<<<g2, 256, 0, stream>>>(x, h1g, c2w, c2b, out_fx, out_logJ);
    } else {
        dim3 grid(6, Nn);
        csplaq_v4_kernel<<<grid, 256, 0, stream>>>(x, c1w, c1b, c2w, c2b, out_fx, out_logJ);
    }
}